// Round 6
// baseline (338.996 us; speedup 1.0000x reference)
//
#include <hip/hip_runtime.h>

#define LL 2048
#define EE 2048
#define DD 1024
#define NC 64    // chunks along L
#define CH 32    // chunk length (NC*CH == LL)

typedef short bf16x8 __attribute__((ext_vector_type(8)));
typedef float f32x4 __attribute__((ext_vector_type(4)));

__device__ inline float bf2f(unsigned short u) {
    union { unsigned u; float f; } v; v.u = ((unsigned)u) << 16; return v.f;
}
__device__ inline unsigned short f2bf(float f) {
    union { float f; unsigned u; } v; v.f = f;
    unsigned r = v.u + 0x7fff + ((v.u >> 16) & 1);
    return (unsigned short)(r >> 16);
}

__device__ inline void gload_lds16(const void* g, void* lds) {
    __builtin_amdgcn_global_load_lds(
        (const __attribute__((address_space(1))) unsigned int*)g,
        (__attribute__((address_space(3))) unsigned int*)lds, 16, 0, 0);
}

// ========== 256xBN GEMM, m201-style 4-phase/K-tile schedule ==========
// Per phase: {ds_read regs; stage prefetch; [vmcnt]; barrier; lgkm(0); MFMA; barrier}
// vmcnt(LH) confirms a k-half ONE PHASE BEFORE the phase that reads it.
// MODE 0: f32 out. MODE 1: bf16 out. MODE 2: softplus(v+bias[col]) -> bf16 out.
template<int MODE, int BN>
__global__ __launch_bounds__(512, 2)
void gemm4p(const unsigned short* __restrict__ A,
            const unsigned short* __restrict__ Bw,
            void* __restrict__ Cout,
            const float* __restrict__ bias,
            int M, int N, int K)
{
    constexpr int NREP = BN / 64;
    constexpr int RB   = BN / 128;
    constexpr int LH   = 2 + RB;     // loads per k-half per thread
    constexpr int NSTRIP = BN / 4;

    extern __shared__ short lds[];
    short* Asm = lds;                    // [2buf][2kh][256][32]
    short* Bsm = lds + 2 * 2 * 256 * 32; // [2buf][2kh][BN][32]

    const int tid = threadIdx.x;
    const int w = tid >> 6, lane = tid & 63;
    const int wm = w >> 2, wn = w & 3;

    const int gx = N / BN;
    const int nwg = gx * (M / 256);
    int lin = blockIdx.y * gx + blockIdx.x;
    int swz = ((nwg & 7) == 0) ? ((lin & 7) * (nwg >> 3) + (lin >> 3)) : lin;
    const long m0 = (long)(swz / gx) * 256;
    const long n0 = (long)(swz % gx) * BN;

    const int g = (tid & 3) ^ ((tid >> 3) & 3);   // inverse-swizzled source slot
    const int arow = tid >> 2;
    const unsigned short* Ag = A + (m0 + arow) * (long)K + g * 8;
    const unsigned short* Bg = Bw + (n0 + arow) * (long)K + g * 8;
    const int ldsrow = w * 16;

    auto stageA = [&](int buf, int kh, int j, int kt) {
        gload_lds16(Ag + (long)j * 128 * K + kt * 64 + kh * 32,
                    Asm + ((buf * 2 + kh) * 256 + j * 128 + ldsrow) * 32);
    };
    auto stageB = [&](int buf, int kh, int j, int kt) {
        gload_lds16(Bg + (long)j * 128 * K + kt * 64 + kh * 32,
                    Bsm + ((buf * 2 + kh) * BN + j * 128 + ldsrow) * 32);
    };

    f32x4 acc[8][NREP] = {};

    // prologue: stage tile 0, both k-halves; confirm kh0 resident
    stageA(0, 0, 0, 0); stageA(0, 0, 1, 0);
#pragma unroll
    for (int j = 0; j < RB; ++j) stageB(0, 0, j, 0);
    stageA(0, 1, 0, 0); stageA(0, 1, 1, 0);
#pragma unroll
    for (int j = 0; j < RB; ++j) stageB(0, 1, j, 0);
    asm volatile("s_waitcnt vmcnt(%0)" :: "i"(LH) : "memory");
    __builtin_amdgcn_s_barrier();

    const int NT = K / 64;
    const int rr = lane & 15;
    const int sl = ((lane >> 4) ^ ((rr >> 1) & 3)) * 8;

    for (int t = 0; t < NT; ++t) {
        const int cur = t & 1, nxt = cur ^ 1;
        const bool more = (t + 1 < NT);
        const short* Ac0 = Asm + (cur * 2 + 0) * 256 * 32;
        const short* Bc0 = Bsm + (cur * 2 + 0) * BN * 32;
        const short* Ac1 = Asm + (cur * 2 + 1) * 256 * 32;
        const short* Bc1 = Bsm + (cur * 2 + 1) * BN * 32;
        bf16x8 a[4], b[NREP];

        // ---- p0: read kh0 {B, A-lo}; stage A-kh0(t+1); MFMA lo/kh0
#pragma unroll
        for (int n = 0; n < NREP; ++n)
            b[n] = *(const bf16x8*)&Bc0[(wn * NSTRIP + n * 16 + rr) * 32 + sl];
#pragma unroll
        for (int m = 0; m < 4; ++m)
            a[m] = *(const bf16x8*)&Ac0[(wm * 128 + m * 16 + rr) * 32 + sl];
        if (more) { stageA(nxt, 0, 0, t + 1); stageA(nxt, 0, 1, t + 1); }
        __builtin_amdgcn_s_barrier();
        asm volatile("s_waitcnt lgkmcnt(0)" ::: "memory");
        __builtin_amdgcn_sched_barrier(0);
        __builtin_amdgcn_s_setprio(1);
#pragma unroll
        for (int m = 0; m < 4; ++m)
#pragma unroll
            for (int n = 0; n < NREP; ++n)
                acc[m][n] = __builtin_amdgcn_mfma_f32_16x16x32_bf16(a[m], b[n], acc[m][n], 0, 0, 0);
        __builtin_amdgcn_s_setprio(0);
        __builtin_amdgcn_s_barrier();

        // ---- p1: read kh0 {A-hi}; stage B-kh0(t+1); vmcnt -> kh1(t) confirmed; MFMA hi/kh0
#pragma unroll
        for (int m = 0; m < 4; ++m)
            a[m] = *(const bf16x8*)&Ac0[(wm * 128 + 64 + m * 16 + rr) * 32 + sl];
        if (more) {
#pragma unroll
            for (int j = 0; j < RB; ++j) stageB(nxt, 0, j, t + 1);
            asm volatile("s_waitcnt vmcnt(%0)" :: "i"(LH) : "memory");
        } else {
            asm volatile("s_waitcnt vmcnt(0)" ::: "memory");
        }
        __builtin_amdgcn_s_barrier();
        asm volatile("s_waitcnt lgkmcnt(0)" ::: "memory");
        __builtin_amdgcn_sched_barrier(0);
        __builtin_amdgcn_s_setprio(1);
#pragma unroll
        for (int m = 0; m < 4; ++m)
#pragma unroll
            for (int n = 0; n < NREP; ++n)
                acc[4 + m][n] = __builtin_amdgcn_mfma_f32_16x16x32_bf16(a[m], b[n], acc[4 + m][n], 0, 0, 0);
        __builtin_amdgcn_s_setprio(0);
        __builtin_amdgcn_s_barrier();

        // ---- p2: read kh1 {B, A-lo}; stage A-kh1(t+1); MFMA lo/kh1
#pragma unroll
        for (int n = 0; n < NREP; ++n)
            b[n] = *(const bf16x8*)&Bc1[(wn * NSTRIP + n * 16 + rr) * 32 + sl];
#pragma unroll
        for (int m = 0; m < 4; ++m)
            a[m] = *(const bf16x8*)&Ac1[(wm * 128 + m * 16 + rr) * 32 + sl];
        if (more) { stageA(nxt, 1, 0, t + 1); stageA(nxt, 1, 1, t + 1); }
        __builtin_amdgcn_s_barrier();
        asm volatile("s_waitcnt lgkmcnt(0)" ::: "memory");
        __builtin_amdgcn_sched_barrier(0);
        __builtin_amdgcn_s_setprio(1);
#pragma unroll
        for (int m = 0; m < 4; ++m)
#pragma unroll
            for (int n = 0; n < NREP; ++n)
                acc[m][n] = __builtin_amdgcn_mfma_f32_16x16x32_bf16(a[m], b[n], acc[m][n], 0, 0, 0);
        __builtin_amdgcn_s_setprio(0);
        __builtin_amdgcn_s_barrier();

        // ---- p3: read kh1 {A-hi}; stage B-kh1(t+1); vmcnt -> kh0(t+1) confirmed; MFMA hi/kh1
#pragma unroll
        for (int m = 0; m < 4; ++m)
            a[m] = *(const bf16x8*)&Ac1[(wm * 128 + 64 + m * 16 + rr) * 32 + sl];
        if (more) {
#pragma unroll
            for (int j = 0; j < RB; ++j) stageB(nxt, 1, j, t + 1);
            asm volatile("s_waitcnt vmcnt(%0)" :: "i"(LH) : "memory");
        }
        __builtin_amdgcn_s_barrier();
        asm volatile("s_waitcnt lgkmcnt(0)" ::: "memory");
        __builtin_amdgcn_sched_barrier(0);
        __builtin_amdgcn_s_setprio(1);
#pragma unroll
        for (int m = 0; m < 4; ++m)
#pragma unroll
            for (int n = 0; n < NREP; ++n)
                acc[4 + m][n] = __builtin_amdgcn_mfma_f32_16x16x32_bf16(a[m], b[n], acc[4 + m][n], 0, 0, 0);
        __builtin_amdgcn_s_setprio(0);
        __builtin_amdgcn_s_barrier();
    }

    // epilogue (layout unchanged)
#pragma unroll
    for (int m = 0; m < 8; ++m) {
#pragma unroll
        for (int n = 0; n < NREP; ++n) {
#pragma unroll
            for (int r = 0; r < 4; ++r) {
                long row = m0 + wm * 128 + m * 16 + (lane >> 4) * 4 + r;
                long col = n0 + wn * NSTRIP + n * 16 + (lane & 15);
                float v = acc[m][n][r];
                if (MODE == 0) {
                    ((float*)Cout)[row * N + col] = v;
                } else if (MODE == 1) {
                    ((unsigned short*)Cout)[row * N + col] = f2bf(v);
                } else {
                    v += bias[col];
                    float sp = (v > 20.f) ? v : log1pf(__expf(v));
                    ((unsigned short*)Cout)[row * N + col] = f2bf(sp);
                }
            }
        }
    }
}

// ============ x_proj split-K GEMM: 128x128 tile, K-slice 256 ============
__global__ __launch_bounds__(256)
void gemm_xp(const unsigned short* __restrict__ A,
             const unsigned short* __restrict__ Bw,
             float* __restrict__ Cout)
{
    __shared__ short As[128 * 32];
    __shared__ short Bs[128 * 32];
    const int tid = threadIdx.x;
    const int wave = tid >> 6, lane = tid & 63;
    const int wm = wave >> 1, wn = wave & 1;
    const long m0 = (long)blockIdx.x * 128;
    const int kz = blockIdx.y;
    float* out = Cout + (long)kz * 8192 * 128;

    f32x4 acc[4][4] = {};

    const int srow = lane >> 2;
    const int g = (lane & 3) ^ ((srow >> 1) & 3);
    const int c0 = wave, c1 = wave + 4;

    for (int k0 = kz * 256; k0 < kz * 256 + 256; k0 += 32) {
        gload_lds16(A + (m0 + c0 * 16 + srow) * 2048L + k0 + g * 8, &As[c0 * 16 * 32]);
        gload_lds16(A + (m0 + c1 * 16 + srow) * 2048L + k0 + g * 8, &As[c1 * 16 * 32]);
        gload_lds16(Bw + (c0 * 16 + srow) * 2048L + k0 + g * 8, &Bs[c0 * 16 * 32]);
        gload_lds16(Bw + (c1 * 16 + srow) * 2048L + k0 + g * 8, &Bs[c1 * 16 * 32]);
        __syncthreads();

        const int rr = lane & 15;
        const int sl = ((lane >> 4) ^ ((rr >> 1) & 3)) * 8;
        bf16x8 af[4], bfr[4];
#pragma unroll
        for (int m = 0; m < 4; ++m)
            af[m] = *(const bf16x8*)&As[(wm * 64 + m * 16 + rr) * 32 + sl];
#pragma unroll
        for (int n = 0; n < 4; ++n)
            bfr[n] = *(const bf16x8*)&Bs[(wn * 64 + n * 16 + rr) * 32 + sl];
#pragma unroll
        for (int m = 0; m < 4; ++m)
#pragma unroll
            for (int n = 0; n < 4; ++n)
                acc[m][n] = __builtin_amdgcn_mfma_f32_16x16x32_bf16(af[m], bfr[n], acc[m][n], 0, 0, 0);
        __syncthreads();
    }

#pragma unroll
    for (int m = 0; m < 4; ++m)
#pragma unroll
        for (int n = 0; n < 4; ++n)
#pragma unroll
            for (int r = 0; r < 4; ++r) {
                long row = m0 + wm * 64 + m * 16 + (lane >> 4) * 4 + r;
                long col = wn * 64 + n * 16 + (lane & 15);
                out[row * 128 + col] = acc[m][n][r];
            }
}

// sum 8 K-partials -> dbc f32; cols < 64 also -> dt bf16
__global__ void reduce_dbc(const float* __restrict__ part,
                           float* __restrict__ dbc,
                           unsigned short* __restrict__ dt)
{
    const long i = (long)blockIdx.x * 256 + threadIdx.x;
    float s = 0.f;
#pragma unroll
    for (int k = 0; k < 8; ++k) s += part[i + (long)k * 1048576];
    dbc[i] = s;
    const int c = (int)(i & 127);
    if (c < 64) dt[(i >> 7) * 64 + c] = f2bf(s);
}

// ---- all f32->bf16 operand conversions in ONE launch ----
__device__ inline void cvt4(const float* __restrict__ in, unsigned short* __restrict__ out, long i) {
    float4 v = ((const float4*)in)[i];
    unsigned lo = (unsigned)f2bf(v.x) | ((unsigned)f2bf(v.y) << 16);
    unsigned hi = (unsigned)f2bf(v.z) | ((unsigned)f2bf(v.w) << 16);
    ((uint2*)out)[i] = make_uint2(lo, hi);
}

__global__ void cvt_all(const float* __restrict__ inp, const float* __restrict__ w_in,
                        const float* __restrict__ w_xp, const float* __restrict__ w_dt,
                        const float* __restrict__ w_out,
                        unsigned short* __restrict__ o_inp, unsigned short* __restrict__ o_win,
                        unsigned short* __restrict__ o_wxp, unsigned short* __restrict__ o_wdt,
                        unsigned short* __restrict__ o_wout)
{
    const long t = (long)blockIdx.x * 256 + threadIdx.x;
    const long gs = (long)gridDim.x * 256;
    for (long i = t; i < 8388608 / 4; i += gs) cvt4(inp, o_inp, i);
    for (long i = t; i < 4194304 / 4; i += gs) cvt4(w_in, o_win, i);
    for (long i = t; i < 2097152 / 4; i += gs) cvt4(w_out, o_wout, i);
    for (long i = t; i < 131072 / 4; i += gs) cvt4(w_dt, o_wdt, i);
    for (long i = t; i < 262144 / 4; i += gs) {
        const int r = (int)(i >> 9);
        if (r < 80) cvt4(w_xp, o_wxp, i);
        else ((uint2*)o_wxp)[i] = make_uint2(0u, 0u);
    }
}

// depthwise causal conv (K=4) + bias + silu; 2 channels per thread (u32 I/O).
__global__ void conv_silu_k(const unsigned short* __restrict__ xz,
                            const float* __restrict__ cw,
                            const float* __restrict__ cb,
                            unsigned short* __restrict__ xc)
{
    const int ep = blockIdx.y * 256 + threadIdx.x;
    const int e0 = ep * 2, e1 = e0 + 1;
    const int b = blockIdx.z;
    const int l0 = blockIdx.x * 32;
    const float wa0 = cw[e0 * 4], wa1 = cw[e0 * 4 + 1], wa2 = cw[e0 * 4 + 2], wa3 = cw[e0 * 4 + 3];
    const float wb0 = cw[e1 * 4], wb1 = cw[e1 * 4 + 1], wb2 = cw[e1 * 4 + 2], wb3 = cw[e1 * 4 + 3];
    const float ba = cb[e0], bb = cb[e1];
    const unsigned* xrow = (const unsigned*)(xz + (long)b * LL * 4096) + ep;
    unsigned* orow = (unsigned*)(xc + (long)b * LL * 2048) + ep;

    float a3 = 0.f, a2 = 0.f, a1 = 0.f, b3 = 0.f, b2 = 0.f, b1 = 0.f;
    if (l0 >= 3) { unsigned u = xrow[(long)(l0 - 3) * 2048]; a3 = bf2f(u & 0xffff); b3 = bf2f(u >> 16); }
    if (l0 >= 2) { unsigned u = xrow[(long)(l0 - 2) * 2048]; a2 = bf2f(u & 0xffff); b2 = bf2f(u >> 16); }
    if (l0 >= 1) { unsigned u = xrow[(long)(l0 - 1) * 2048]; a1 = bf2f(u & 0xffff); b1 = bf2f(u >> 16); }
    for (int l = l0; l < l0 + 32; ++l) {
        unsigned u = xrow[(long)l * 2048];
        float xa = bf2f(u & 0xffff), xb = bf2f(u >> 16);
        float va = ba + wa0 * a3 + wa1 * a2 + wa2 * a1 + wa3 * xa;
        float vb = bb + wb0 * b3 + wb1 * b2 + wb2 * b1 + wb3 * xb;
        float sa = va / (1.f + __expf(-va));
        float sb = vb / (1.f + __expf(-vb));
        orow[(long)l * 1024] = (unsigned)f2bf(sa) | ((unsigned)f2bf(sb) << 16);
        a3 = a2; a2 = a1; a1 = xa;
        b3 = b2; b2 = b1; b1 = xb;
    }
}

// ------- chunked parallel SSM scan, 2 channels/thread (NC=64, CH=32) -------
__global__ __launch_bounds__(256)
void scan_local(const unsigned short* __restrict__ delta,
                const unsigned short* __restrict__ xconv,
                const float* __restrict__ dbc,
                const float* __restrict__ A_log,
                float* __restrict__ hend, float* __restrict__ Ssum)
{
    const int ep = blockIdx.x * 256 + threadIdx.x;   // e-pair 0..1023
    const int e0 = ep * 2;
    const int c = blockIdx.y, b = blockIdx.z;
    const int l0 = c * CH;
    float An[16];
#pragma unroll
    for (int n = 0; n < 16; ++n) An[n] = -__expf(A_log[e0 * 8 + n]);
    float h[16] = {};
    float S0 = 0.f, S1 = 0.f;
    const unsigned* drow = (const unsigned*)(delta + ((long)b * LL + l0) * EE) + ep;
    const unsigned* urow = (const unsigned*)(xconv + ((long)b * LL + l0) * EE) + ep;
    const float* bc = dbc + ((long)b * LL + l0) * 128;
    for (int l = 0; l < CH; ++l) {
        unsigned dv = drow[(long)l * 1024];
        unsigned uv = urow[(long)l * 1024];
        float d0 = bf2f(dv & 0xffff), d1 = bf2f(dv >> 16);
        float u0 = bf2f(uv & 0xffff), u1 = bf2f(uv >> 16);
        float du0 = d0 * u0, du1 = d1 * u1;
        S0 += d0; S1 += d1;
#pragma unroll
        for (int n = 0; n < 8; ++n) {
            float bn = bc[l * 128 + 64 + n];
            h[n]     = h[n]     * __expf(d0 * An[n])     + du0 * bn;
            h[8 + n] = h[8 + n] * __expf(d1 * An[8 + n]) + du1 * bn;
        }
    }
    const long o = ((long)b * NC + c) * EE + e0;
#pragma unroll
    for (int n = 0; n < 8; ++n) { hend[o * 8 + n] = h[n]; hend[(o + 1) * 8 + n] = h[8 + n]; }
    Ssum[o] = S0; Ssum[o + 1] = S1;
}

__global__ __launch_bounds__(256)
void scan_combine(const float* __restrict__ hend, const float* __restrict__ Ssum,
                  const float* __restrict__ A_log, float* __restrict__ hin)
{
    const int t = blockIdx.x * 256 + threadIdx.x;
    const int b = t >> 11, e = t & 2047;
    float An[8];
#pragma unroll
    for (int n = 0; n < 8; ++n) An[n] = -__expf(A_log[e * 8 + n]);
    float h[8] = {};
    for (int c = 0; c < NC; ++c) {
        const long o = ((long)b * NC + c) * EE + e;
#pragma unroll
        for (int n = 0; n < 8; ++n) hin[o * 8 + n] = h[n];
        float S = Ssum[o];
#pragma unroll
        for (int n = 0; n < 8; ++n)
            h[n] = h[n] * __expf(An[n] * S) + hend[o * 8 + n];
    }
}

__global__ __launch_bounds__(256)
void scan_final(const unsigned short* __restrict__ delta,
                const unsigned short* __restrict__ xconv,
                const float* __restrict__ dbc,
                const unsigned short* __restrict__ xz,
                const float* __restrict__ A_log,
                const float* __restrict__ Dparam,
                const float* __restrict__ hin,
                unsigned short* __restrict__ yg)
{
    const int ep = blockIdx.x * 256 + threadIdx.x;
    const int e0 = ep * 2;
    const int c = blockIdx.y, b = blockIdx.z;
    const int l0 = c * CH;
    float An[16];
#pragma unroll
    for (int n = 0; n < 16; ++n) An[n] = -__expf(A_log[e0 * 8 + n]);
    const float Dp0 = Dparam[e0], Dp1 = Dparam[e0 + 1];
    float h[16];
    const long o = ((long)b * NC + c) * EE + e0;
#pragma unroll
    for (int n = 0; n < 8; ++n) { h[n] = hin[o * 8 + n]; h[8 + n] = hin[(o + 1) * 8 + n]; }
    const unsigned* drow = (const unsigned*)(delta + ((long)b * LL + l0) * EE) + ep;
    const unsigned* urow = (const unsigned*)(xconv + ((long)b * LL + l0) * EE) + ep;
    const unsigned* zrow = (const unsigned*)(xz + ((long)b * LL + l0) * 4096 + 2048) + ep;
    const float* bc = dbc + ((long)b * LL + l0) * 128;
    unsigned* yrow = (unsigned*)(yg + ((long)b * LL + l0) * EE) + ep;
    for (int l = 0; l < CH; ++l) {
        unsigned dv = drow[(long)l * 1024];
        unsigned uv = urow[(long)l * 1024];
        float d0 = bf2f(dv & 0xffff), d1 = bf2f(dv >> 16);
        float u0 = bf2f(uv & 0xffff), u1 = bf2f(uv >> 16);
        float du0 = d0 * u0, du1 = d1 * u1;
        float y0 = 0.f, y1 = 0.f;
#pragma unroll
        for (int n = 0; n < 8; ++n) {
            float bn = bc[l * 128 + 64 + n];
            float cn = bc[l * 128 + 72 + n];
            h[n]     = h[n]     * __expf(d0 * An[n])     + du0 * bn;
            h[8 + n] = h[8 + n] * __expf(d1 * An[8 + n]) + du1 * bn;
            y0 += h[n] * cn;
            y1 += h[8 + n] * cn;
        }
        y0 += u0 * Dp0; y1 += u1 * Dp1;
        unsigned zv = zrow[(long)l * 2048];
        float z0 = bf2f(zv & 0xffff), z1 = bf2f(zv >> 16);
        float g0 = z0 / (1.f + __expf(-z0));
        float g1 = z1 / (1.f + __expf(-z1));
        yrow[(long)l * 1024] = (unsigned)f2bf(y0 * g0) | ((unsigned)f2bf(y1 * g1) << 16);
    }
}

__global__ __launch_bounds__(256)
void rmsnorm_k(const unsigned short* __restrict__ in, const float* __restrict__ w,
               float* __restrict__ out)
{
    const int row = blockIdx.x;
    uint2 v2 = *(const uint2*)(in + (long)row * 1024 + threadIdx.x * 4);
    float x0 = bf2f(v2.x & 0xffff), x1 = bf2f(v2.x >> 16);
    float x2 = bf2f(v2.y & 0xffff), x3 = bf2f(v2.y >> 16);
    float ss = x0 * x0 + x1 * x1 + x2 * x2 + x3 * x3;
#pragma unroll
    for (int m = 32; m >= 1; m >>= 1) ss += __shfl_xor(ss, m, 64);
    __shared__ float wsum[4];
    const int wave = threadIdx.x >> 6;
    if ((threadIdx.x & 63) == 0) wsum[wave] = ss;
    __syncthreads();
    float tot = wsum[0] + wsum[1] + wsum[2] + wsum[3];
    float sc = rsqrtf(tot * (1.f / 1024.f) + 1e-5f);
    float4 wv = ((const float4*)w)[threadIdx.x];
    float4 o;
    o.x = x0 * sc * wv.x; o.y = x1 * sc * wv.y;
    o.z = x2 * sc * wv.z; o.w = x3 * sc * wv.w;
    ((float4*)(out + (long)row * 1024))[threadIdx.x] = o;
}

extern "C" void kernel_launch(void* const* d_in, const int* in_sizes, int n_in,
                              void* d_out, int out_size, void* d_ws, size_t ws_size,
                              hipStream_t stream)
{
    const float* inp   = (const float*)d_in[0];
    const float* w_in  = (const float*)d_in[1];
    const float* convw = (const float*)d_in[2];
    const float* convb = (const float*)d_in[3];
    const float* w_xp  = (const float*)d_in[4];
    const float* w_dt  = (const float*)d_in[5];
    const float* b_dt  = (const float*)d_in[6];
    const float* A_log = (const float*)d_in[7];
    const float* Dp    = (const float*)d_in[8];
    const float* w_out = (const float*)d_in[9];
    const float* rmsw  = (const float*)d_in[10];

    char* ws = (char*)d_ws;
    const size_t MB = 1024 * 1024;
    unsigned short* inp_bf   = (unsigned short*)(ws + 0);        // 16MB (dead after GEMM1)
    unsigned short* win_bf   = (unsigned short*)(ws + 16 * MB);  // 8MB  (dead after GEMM1)
    unsigned short* xz_bf    = (unsigned short*)(ws + 24 * MB);  // 64MB (live until scan_final)
    unsigned short* xconv_bf = (unsigned short*)(ws + 88 * MB);  // 32MB
    unsigned short* wxp_bf   = (unsigned short*)(ws + 120 * MB); // 0.5MB
    float*          dbc      = (float*)(ws + 121 * MB);          // 4MB
    unsigned short* dt_bf    = (unsigned short*)(ws + 125 * MB); // 1MB
    unsigned short* wdt_bf   = (unsigned short*)(ws + 126 * MB); // 0.25MB
    unsigned short* delta_bf = (unsigned short*)(ws + 127 * MB); // 32MB
    unsigned short* yg_bf    = (unsigned short*)(ws + 191 * MB); // 32MB
    unsigned short* wout_bf  = (unsigned short*)(ws + 223 * MB); // 4MB
    float*          dbc_part = (float*)(ws + 159 * MB);          // 32MB (xp partials)
    float*          hend     = (float*)(ws + 159 * MB);          // 16MB (after reduce)
    float*          hin      = (float*)(ws + 175 * MB);          // 16MB
    float*          Ssum     = (float*)(ws + 0);                 // 2MB  (over dead inp_bf)
    unsigned short* out_pre  = (unsigned short*)(ws + 0);        // 16MB bf16 (after scans)

    hipFuncSetAttribute((const void*)gemm4p<1, 256>, hipFuncAttributeMaxDynamicSharedMemorySize, 131072);
    hipFuncSetAttribute((const void*)gemm4p<2, 128>, hipFuncAttributeMaxDynamicSharedMemorySize, 98304);
    hipFuncSetAttribute((const void*)gemm4p<1, 128>, hipFuncAttributeMaxDynamicSharedMemorySize, 98304);

    cvt_all<<<2048, 256, 0, stream>>>(inp, w_in, w_xp, w_dt, w_out,
                                      inp_bf, win_bf, wxp_bf, wdt_bf, wout_bf);

    // xz = inp @ in_proj_w^T (8192 x 4096, K=1024) -> bf16
    gemm4p<1, 256><<<dim3(16, 32), 512, 131072, stream>>>(inp_bf, win_bf, xz_bf, nullptr, 8192, 4096, 1024);
    // depthwise causal conv + silu
    conv_silu_k<<<dim3(64, 4, 4), 256, 0, stream>>>(xz_bf, convw, convb, xconv_bf);
    // dbc partials: xconv @ x_proj_w^T split-K (8 x 256)
    gemm_xp<<<dim3(64, 8), 256, 0, stream>>>(xconv_bf, wxp_bf, dbc_part);
    // reduce partials -> dbc f32 + dt bf16
    reduce_dbc<<<4096, 256, 0, stream>>>(dbc_part, dbc, dt_bf);
    // delta = softplus(dt @ dt_proj_w^T + b) (8192 x 2048, K=64) -> bf16
    gemm4p<2, 128><<<dim3(16, 32), 512, 98304, stream>>>(dt_bf, wdt_bf, delta_bf, b_dt, 8192, 2048, 64);
    // chunked parallel SSM scan (2 channels/thread)
    scan_local<<<dim3(4, NC, 4), 256, 0, stream>>>(delta_bf, xconv_bf, dbc, A_log, hend, Ssum);
    scan_combine<<<32, 256, 0, stream>>>(hend, Ssum, A_log, hin);
    scan_final<<<dim3(4, NC, 4), 256, 0, stream>>>(delta_bf, xconv_bf, dbc, xz_bf, A_log, Dp, hin, yg_bf);
    // out_pre = ygated @ out_proj_w^T (8192 x 1024, K=2048) -> bf16
    gemm4p<1, 128><<<dim3(8, 32), 512, 98304, stream>>>(yg_bf, wout_bf, out_pre, nullptr, 8192, 1024, 2048);
    // RMSNorm (bf16 in, f32 out)
    rmsnorm_k<<<8192, 256, 0, stream>>>(out_pre, rmsw, (float*)d_out);
}

// Round 7
// 323.441 us; speedup vs baseline: 1.0481x; 1.0481x over previous
//
#include <hip/hip_runtime.h>

#define LL 2048
#define EE 2048
#define DD 1024
#define NC 64    // chunks along L
#define CH 32    // chunk length (NC*CH == LL)

typedef short bf16x8 __attribute__((ext_vector_type(8)));
typedef float f32x4 __attribute__((ext_vector_type(4)));

__device__ inline float bf2f(unsigned short u) {
    union { unsigned u; float f; } v; v.u = ((unsigned)u) << 16; return v.f;
}
__device__ inline unsigned short f2bf(float f) {
    union { float f; unsigned u; } v; v.f = f;
    unsigned r = v.u + 0x7fff + ((v.u >> 16) & 1);
    return (unsigned short)(r >> 16);
}

__device__ inline void gload_lds16(const void* g, void* lds) {
    __builtin_amdgcn_global_load_lds(
        (const __attribute__((address_space(1))) unsigned int*)g,
        (__attribute__((address_space(3))) unsigned int*)lds, 16, 0, 0);
}

// ================= 256xBN 8-phase counted-vmcnt GEMM (R5-frozen) =================
// MODE 0: f32 out. MODE 1: bf16 out.
template<int MODE, int BN>
__global__ __launch_bounds__(512, 2)
void gemm8p(const unsigned short* __restrict__ A,
            const unsigned short* __restrict__ Bw,
            void* __restrict__ Cout,
            int M, int N, int K)
{
    constexpr int NREP = BN / 64;
    constexpr int RB   = BN / 128;
    constexpr int LH   = 2 + RB;
    constexpr int NSTRIP = BN / 4;

    extern __shared__ short lds[];
    short* Asm = lds;                    // [2buf][2kh][256][32]
    short* Bsm = lds + 2 * 2 * 256 * 32; // [2buf][2kh][BN][32]

    const int tid = threadIdx.x;
    const int w = tid >> 6, lane = tid & 63;
    const int wm = w >> 2, wn = w & 3;

    const int gx = N / BN;
    const int nwg = gx * (M / 256);
    int lin = blockIdx.y * gx + blockIdx.x;
    int swz = ((nwg & 7) == 0) ? ((lin & 7) * (nwg >> 3) + (lin >> 3)) : lin;
    const long m0 = (long)(swz / gx) * 256;
    const long n0 = (long)(swz % gx) * BN;

    const int g = (tid & 3) ^ ((tid >> 3) & 3);
    const int arow = tid >> 2;
    const unsigned short* Ag = A + (m0 + arow) * (long)K + g * 8;
    const unsigned short* Bg = Bw + (n0 + arow) * (long)K + g * 8;
    const int ldsrow = w * 16;

    auto stageA = [&](int buf, int kh, int j, int kt) {
        gload_lds16(Ag + (long)j * 128 * K + kt * 64 + kh * 32,
                    Asm + ((buf * 2 + kh) * 256 + j * 128 + ldsrow) * 32);
    };
    auto stageB = [&](int buf, int kh, int j, int kt) {
        gload_lds16(Bg + (long)j * 128 * K + kt * 64 + kh * 32,
                    Bsm + ((buf * 2 + kh) * BN + j * 128 + ldsrow) * 32);
    };

    f32x4 acc[8][NREP] = {};

    stageA(0, 0, 0, 0); stageA(0, 0, 1, 0);
#pragma unroll
    for (int j = 0; j < RB; ++j) stageB(0, 0, j, 0);
    stageA(0, 1, 0, 0); stageA(0, 1, 1, 0);
#pragma unroll
    for (int j = 0; j < RB; ++j) stageB(0, 1, j, 0);

    const int NT = K / 64;
    const int rr = lane & 15;
    const int sl = ((lane >> 4) ^ ((rr >> 1) & 3)) * 8;

    for (int t = 0; t < NT; ++t) {
        const int cur = t & 1, nxt = cur ^ 1;
        const bool more = (t + 1 < NT);

        asm volatile("s_waitcnt vmcnt(%0)" :: "i"(LH) : "memory");
        __builtin_amdgcn_s_barrier();

        const short* Ac0 = Asm + (cur * 2 + 0) * 256 * 32;
        const short* Bc0 = Bsm + (cur * 2 + 0) * BN * 32;
        if (more) { stageA(nxt, 0, 0, t + 1); stageA(nxt, 0, 1, t + 1); }
        bf16x8 a[4], b[NREP];
#pragma unroll
        for (int m = 0; m < 4; ++m)
            a[m] = *(const bf16x8*)&Ac0[(wm * 128 + m * 16 + rr) * 32 + sl];
#pragma unroll
        for (int n = 0; n < NREP; ++n)
            b[n] = *(const bf16x8*)&Bc0[(wn * NSTRIP + n * 16 + rr) * 32 + sl];
        __builtin_amdgcn_s_setprio(1);
#pragma unroll
        for (int m = 0; m < 4; ++m)
#pragma unroll
            for (int n = 0; n < NREP; ++n)
                acc[m][n] = __builtin_amdgcn_mfma_f32_16x16x32_bf16(a[m], b[n], acc[m][n], 0, 0, 0);
        __builtin_amdgcn_s_setprio(0);
        if (more) {
#pragma unroll
            for (int j = 0; j < RB; ++j) stageB(nxt, 0, j, t + 1);
        }
#pragma unroll
        for (int m = 0; m < 4; ++m)
            a[m] = *(const bf16x8*)&Ac0[(wm * 128 + 64 + m * 16 + rr) * 32 + sl];
        __builtin_amdgcn_s_setprio(1);
#pragma unroll
        for (int m = 0; m < 4; ++m)
#pragma unroll
            for (int n = 0; n < NREP; ++n)
                acc[4 + m][n] = __builtin_amdgcn_mfma_f32_16x16x32_bf16(a[m], b[n], acc[4 + m][n], 0, 0, 0);
        __builtin_amdgcn_s_setprio(0);

        if (more) { asm volatile("s_waitcnt vmcnt(%0)" :: "i"(LH) : "memory"); }
        else      { asm volatile("s_waitcnt vmcnt(0)" ::: "memory"); }
        __builtin_amdgcn_s_barrier();

        const short* Ac1 = Asm + (cur * 2 + 1) * 256 * 32;
        const short* Bc1 = Bsm + (cur * 2 + 1) * BN * 32;
        if (more) { stageA(nxt, 1, 0, t + 1); stageA(nxt, 1, 1, t + 1); }
#pragma unroll
        for (int m = 0; m < 4; ++m)
            a[m] = *(const bf16x8*)&Ac1[(wm * 128 + m * 16 + rr) * 32 + sl];
#pragma unroll
        for (int n = 0; n < NREP; ++n)
            b[n] = *(const bf16x8*)&Bc1[(wn * NSTRIP + n * 16 + rr) * 32 + sl];
        __builtin_amdgcn_s_setprio(1);
#pragma unroll
        for (int m = 0; m < 4; ++m)
#pragma unroll
            for (int n = 0; n < NREP; ++n)
                acc[m][n] = __builtin_amdgcn_mfma_f32_16x16x32_bf16(a[m], b[n], acc[m][n], 0, 0, 0);
        __builtin_amdgcn_s_setprio(0);
        if (more) {
#pragma unroll
            for (int j = 0; j < RB; ++j) stageB(nxt, 1, j, t + 1);
        }
#pragma unroll
        for (int m = 0; m < 4; ++m)
            a[m] = *(const bf16x8*)&Ac1[(wm * 128 + 64 + m * 16 + rr) * 32 + sl];
        __builtin_amdgcn_s_setprio(1);
#pragma unroll
        for (int m = 0; m < 4; ++m)
#pragma unroll
            for (int n = 0; n < NREP; ++n)
                acc[4 + m][n] = __builtin_amdgcn_mfma_f32_16x16x32_bf16(a[m], b[n], acc[4 + m][n], 0, 0, 0);
        __builtin_amdgcn_s_setprio(0);
    }

#pragma unroll
    for (int m = 0; m < 8; ++m) {
#pragma unroll
        for (int n = 0; n < NREP; ++n) {
#pragma unroll
            for (int r = 0; r < 4; ++r) {
                long row = m0 + wm * 128 + m * 16 + (lane >> 4) * 4 + r;
                long col = n0 + wn * NSTRIP + n * 16 + (lane & 15);
                float v = acc[m][n][r];
                if (MODE == 0) ((float*)Cout)[row * N + col] = v;
                else           ((unsigned short*)Cout)[row * N + col] = f2bf(v);
            }
        }
    }
}

// ============ x_proj split-K GEMM: 128x128 tile, K-slice 512, kz 0..3 ============
__global__ __launch_bounds__(256)
void gemm_xp(const unsigned short* __restrict__ A,
             const unsigned short* __restrict__ Bw,
             float* __restrict__ Cout)
{
    __shared__ short As[128 * 32];
    __shared__ short Bs[128 * 32];
    const int tid = threadIdx.x;
    const int wave = tid >> 6, lane = tid & 63;
    const int wm = wave >> 1, wn = wave & 1;
    const long m0 = (long)blockIdx.x * 128;
    const int kz = blockIdx.y;
    float* out = Cout + (long)kz * 8192 * 128;

    f32x4 acc[4][4] = {};

    const int srow = lane >> 2;
    const int g = (lane & 3) ^ ((srow >> 1) & 3);
    const int c0 = wave, c1 = wave + 4;

    for (int k0 = kz * 512; k0 < kz * 512 + 512; k0 += 32) {
        gload_lds16(A + (m0 + c0 * 16 + srow) * 2048L + k0 + g * 8, &As[c0 * 16 * 32]);
        gload_lds16(A + (m0 + c1 * 16 + srow) * 2048L + k0 + g * 8, &As[c1 * 16 * 32]);
        gload_lds16(Bw + (c0 * 16 + srow) * 2048L + k0 + g * 8, &Bs[c0 * 16 * 32]);
        gload_lds16(Bw + (c1 * 16 + srow) * 2048L + k0 + g * 8, &Bs[c1 * 16 * 32]);
        __syncthreads();

        const int rr = lane & 15;
        const int sl = ((lane >> 4) ^ ((rr >> 1) & 3)) * 8;
        bf16x8 af[4], bfr[4];
#pragma unroll
        for (int m = 0; m < 4; ++m)
            af[m] = *(const bf16x8*)&As[(wm * 64 + m * 16 + rr) * 32 + sl];
#pragma unroll
        for (int n = 0; n < 4; ++n)
            bfr[n] = *(const bf16x8*)&Bs[(wn * 64 + n * 16 + rr) * 32 + sl];
#pragma unroll
        for (int m = 0; m < 4; ++m)
#pragma unroll
            for (int n = 0; n < 4; ++n)
                acc[m][n] = __builtin_amdgcn_mfma_f32_16x16x32_bf16(af[m], bfr[n], acc[m][n], 0, 0, 0);
        __syncthreads();
    }

#pragma unroll
    for (int m = 0; m < 4; ++m)
#pragma unroll
        for (int n = 0; n < 4; ++n)
#pragma unroll
            for (int r = 0; r < 4; ++r) {
                long row = m0 + wm * 64 + m * 16 + (lane >> 4) * 4 + r;
                long col = wn * 64 + n * 16 + (lane & 15);
                out[row * 128 + col] = acc[m][n][r];
            }
}

// sum 4 K-partials -> dbc f32; cols < 64 also -> dt bf16
__global__ void reduce_dbc(const float* __restrict__ part,
                           float* __restrict__ dbc,
                           unsigned short* __restrict__ dt)
{
    const long i = (long)blockIdx.x * 256 + threadIdx.x;
    float s = part[i] + part[i + 1048576] + part[i + 2 * 1048576] + part[i + 3 * 1048576];
    dbc[i] = s;
    const int c = (int)(i & 127);
    if (c < 64) dt[(i >> 7) * 64 + c] = f2bf(s);
}

// ===== dt_proj: light 128x128 2-phase GEMM, K=64 (16KB LDS -> multi-block/CU) =====
// delta = softplus(dt @ wdt^T + bias) -> bf16.  A: 8192x64, Bw: 2048x64.
__global__ __launch_bounds__(256)
void gemm_dt(const unsigned short* __restrict__ A,
             const unsigned short* __restrict__ Bw,
             const float* __restrict__ bias,
             unsigned short* __restrict__ Cout)
{
    __shared__ short As[128 * 32];
    __shared__ short Bs[128 * 32];
    const int tid = threadIdx.x;
    const int wave = tid >> 6, lane = tid & 63;
    const int wm = wave >> 1, wn = wave & 1;
    const long m0 = (long)blockIdx.y * 128;
    const long n0 = (long)blockIdx.x * 128;

    f32x4 acc[4][4] = {};

    const int srow = lane >> 2;
    const int g = (lane & 3) ^ ((srow >> 1) & 3);
    const int c0 = wave, c1 = wave + 4;

    for (int k0 = 0; k0 < 64; k0 += 32) {
        gload_lds16(A + (m0 + c0 * 16 + srow) * 64L + k0 + g * 8, &As[c0 * 16 * 32]);
        gload_lds16(A + (m0 + c1 * 16 + srow) * 64L + k0 + g * 8, &As[c1 * 16 * 32]);
        gload_lds16(Bw + (n0 + c0 * 16 + srow) * 64L + k0 + g * 8, &Bs[c0 * 16 * 32]);
        gload_lds16(Bw + (n0 + c1 * 16 + srow) * 64L + k0 + g * 8, &Bs[c1 * 16 * 32]);
        __syncthreads();

        const int rr = lane & 15;
        const int sl = ((lane >> 4) ^ ((rr >> 1) & 3)) * 8;
        bf16x8 af[4], bfr[4];
#pragma unroll
        for (int m = 0; m < 4; ++m)
            af[m] = *(const bf16x8*)&As[(wm * 64 + m * 16 + rr) * 32 + sl];
#pragma unroll
        for (int n = 0; n < 4; ++n)
            bfr[n] = *(const bf16x8*)&Bs[(wn * 64 + n * 16 + rr) * 32 + sl];
#pragma unroll
        for (int m = 0; m < 4; ++m)
#pragma unroll
            for (int n = 0; n < 4; ++n)
                acc[m][n] = __builtin_amdgcn_mfma_f32_16x16x32_bf16(af[m], bfr[n], acc[m][n], 0, 0, 0);
        __syncthreads();
    }

#pragma unroll
    for (int m = 0; m < 4; ++m)
#pragma unroll
        for (int n = 0; n < 4; ++n)
#pragma unroll
            for (int r = 0; r < 4; ++r) {
                long row = m0 + wm * 64 + m * 16 + (lane >> 4) * 4 + r;
                long col = n0 + wn * 64 + n * 16 + (lane & 15);
                float v = acc[m][n][r] + bias[col];
                float sp = (v > 20.f) ? v : log1pf(__expf(v));
                Cout[row * 2048 + col] = f2bf(sp);
            }
}

// ---- all f32->bf16 operand conversions in ONE launch ----
__device__ inline void cvt4(const float* __restrict__ in, unsigned short* __restrict__ out, long i) {
    float4 v = ((const float4*)in)[i];
    unsigned lo = (unsigned)f2bf(v.x) | ((unsigned)f2bf(v.y) << 16);
    unsigned hi = (unsigned)f2bf(v.z) | ((unsigned)f2bf(v.w) << 16);
    ((uint2*)out)[i] = make_uint2(lo, hi);
}

__global__ void cvt_all(const float* __restrict__ inp, const float* __restrict__ w_in,
                        const float* __restrict__ w_xp, const float* __restrict__ w_dt,
                        const float* __restrict__ w_out,
                        unsigned short* __restrict__ o_inp, unsigned short* __restrict__ o_win,
                        unsigned short* __restrict__ o_wxp, unsigned short* __restrict__ o_wdt,
                        unsigned short* __restrict__ o_wout)
{
    const long t = (long)blockIdx.x * 256 + threadIdx.x;
    const long gs = (long)gridDim.x * 256;
    for (long i = t; i < 8388608 / 4; i += gs) cvt4(inp, o_inp, i);
    for (long i = t; i < 4194304 / 4; i += gs) cvt4(w_in, o_win, i);
    for (long i = t; i < 2097152 / 4; i += gs) cvt4(w_out, o_wout, i);
    for (long i = t; i < 131072 / 4; i += gs) cvt4(w_dt, o_wdt, i);
    for (long i = t; i < 262144 / 4; i += gs) {
        const int r = (int)(i >> 9);
        if (r < 80) cvt4(w_xp, o_wxp, i);
        else ((uint2*)o_wxp)[i] = make_uint2(0u, 0u);
    }
}

// depthwise causal conv (K=4) + bias + silu; 2 channels per thread (u32 I/O).
__global__ void conv_silu_k(const unsigned short* __restrict__ xz,
                            const float* __restrict__ cw,
                            const float* __restrict__ cb,
                            unsigned short* __restrict__ xc)
{
    const int ep = blockIdx.y * 256 + threadIdx.x;
    const int e0 = ep * 2, e1 = e0 + 1;
    const int b = blockIdx.z;
    const int l0 = blockIdx.x * 32;
    const float wa0 = cw[e0 * 4], wa1 = cw[e0 * 4 + 1], wa2 = cw[e0 * 4 + 2], wa3 = cw[e0 * 4 + 3];
    const float wb0 = cw[e1 * 4], wb1 = cw[e1 * 4 + 1], wb2 = cw[e1 * 4 + 2], wb3 = cw[e1 * 4 + 3];
    const float ba = cb[e0], bb = cb[e1];
    const unsigned* xrow = (const unsigned*)(xz + (long)b * LL * 4096) + ep;
    unsigned* orow = (unsigned*)(xc + (long)b * LL * 2048) + ep;

    float a3 = 0.f, a2 = 0.f, a1 = 0.f, b3 = 0.f, b2 = 0.f, b1 = 0.f;
    if (l0 >= 3) { unsigned u = xrow[(long)(l0 - 3) * 2048]; a3 = bf2f(u & 0xffff); b3 = bf2f(u >> 16); }
    if (l0 >= 2) { unsigned u = xrow[(long)(l0 - 2) * 2048]; a2 = bf2f(u & 0xffff); b2 = bf2f(u >> 16); }
    if (l0 >= 1) { unsigned u = xrow[(long)(l0 - 1) * 2048]; a1 = bf2f(u & 0xffff); b1 = bf2f(u >> 16); }
    for (int l = l0; l < l0 + 32; ++l) {
        unsigned u = xrow[(long)l * 2048];
        float xa = bf2f(u & 0xffff), xb = bf2f(u >> 16);
        float va = ba + wa0 * a3 + wa1 * a2 + wa2 * a1 + wa3 * xa;
        float vb = bb + wb0 * b3 + wb1 * b2 + wb2 * b1 + wb3 * xb;
        float sa = va / (1.f + __expf(-va));
        float sb = vb / (1.f + __expf(-vb));
        orow[(long)l * 1024] = (unsigned)f2bf(sa) | ((unsigned)f2bf(sb) << 16);
        a3 = a2; a2 = a1; a1 = xa;
        b3 = b2; b2 = b1; b1 = xb;
    }
}

// ------- chunked parallel SSM scan, 2 channels/thread (NC=64, CH=32) -------
__global__ __launch_bounds__(256)
void scan_local(const unsigned short* __restrict__ delta,
                const unsigned short* __restrict__ xconv,
                const float* __restrict__ dbc,
                const float* __restrict__ A_log,
                float* __restrict__ hend, float* __restrict__ Ssum)
{
    const int ep = blockIdx.x * 256 + threadIdx.x;
    const int e0 = ep * 2;
    const int c = blockIdx.y, b = blockIdx.z;
    const int l0 = c * CH;
    float An[16];
#pragma unroll
    for (int n = 0; n < 16; ++n) An[n] = -__expf(A_log[e0 * 8 + n]);
    float h[16] = {};
    float S0 = 0.f, S1 = 0.f;
    const unsigned* drow = (const unsigned*)(delta + ((long)b * LL + l0) * EE) + ep;
    const unsigned* urow = (const unsigned*)(xconv + ((long)b * LL + l0) * EE) + ep;
    const float* bc = dbc + ((long)b * LL + l0) * 128;
    for (int l = 0; l < CH; ++l) {
        unsigned dv = drow[(long)l * 1024];
        unsigned uv = urow[(long)l * 1024];
        float d0 = bf2f(dv & 0xffff), d1 = bf2f(dv >> 16);
        float u0 = bf2f(uv & 0xffff), u1 = bf2f(uv >> 16);
        float du0 = d0 * u0, du1 = d1 * u1;
        S0 += d0; S1 += d1;
#pragma unroll
        for (int n = 0; n < 8; ++n) {
            float bn = bc[l * 128 + 64 + n];
            h[n]     = h[n]     * __expf(d0 * An[n])     + du0 * bn;
            h[8 + n] = h[8 + n] * __expf(d1 * An[8 + n]) + du1 * bn;
        }
    }
    const long o = ((long)b * NC + c) * EE + e0;
#pragma unroll
    for (int n = 0; n < 8; ++n) { hend[o * 8 + n] = h[n]; hend[(o + 1) * 8 + n] = h[8 + n]; }
    Ssum[o] = S0; Ssum[o + 1] = S1;
}

// combine parallelized over (b,e,n): 65536 threads = 256 blocks (was 32).
__global__ __launch_bounds__(256)
void scan_combine(const float* __restrict__ hend, const float* __restrict__ Ssum,
                  const float* __restrict__ A_log, float* __restrict__ hin)
{
    const int t = blockIdx.x * 256 + threadIdx.x;   // over B*E*8 = 65536
    const int n = t & 7;
    const int be = t >> 3;
    const int b = be >> 11, e = be & 2047;
    const float An = -__expf(A_log[e * 8 + n]);
    float h = 0.f;
    for (int c = 0; c < NC; ++c) {
        const long o = ((long)b * NC + c) * EE + e;
        hin[o * 8 + n] = h;
        h = h * __expf(An * Ssum[o]) + hend[o * 8 + n];
    }
}

__global__ __launch_bounds__(256)
void scan_final(const unsigned short* __restrict__ delta,
                const unsigned short* __restrict__ xconv,
                const float* __restrict__ dbc,
                const unsigned short* __restrict__ xz,
                const float* __restrict__ A_log,
                const float* __restrict__ Dparam,
                const float* __restrict__ hin,
                unsigned short* __restrict__ yg)
{
    const int ep = blockIdx.x * 256 + threadIdx.x;
    const int e0 = ep * 2;
    const int c = blockIdx.y, b = blockIdx.z;
    const int l0 = c * CH;
    float An[16];
#pragma unroll
    for (int n = 0; n < 16; ++n) An[n] = -__expf(A_log[e0 * 8 + n]);
    const float Dp0 = Dparam[e0], Dp1 = Dparam[e0 + 1];
    float h[16];
    const long o = ((long)b * NC + c) * EE + e0;
#pragma unroll
    for (int n = 0; n < 8; ++n) { h[n] = hin[o * 8 + n]; h[8 + n] = hin[(o + 1) * 8 + n]; }
    const unsigned* drow = (const unsigned*)(delta + ((long)b * LL + l0) * EE) + ep;
    const unsigned* urow = (const unsigned*)(xconv + ((long)b * LL + l0) * EE) + ep;
    const unsigned* zrow = (const unsigned*)(xz + ((long)b * LL + l0) * 4096 + 2048) + ep;
    const float* bc = dbc + ((long)b * LL + l0) * 128;
    unsigned* yrow = (unsigned*)(yg + ((long)b * LL + l0) * EE) + ep;
    for (int l = 0; l < CH; ++l) {
        unsigned dv = drow[(long)l * 1024];
        unsigned uv = urow[(long)l * 1024];
        float d0 = bf2f(dv & 0xffff), d1 = bf2f(dv >> 16);
        float u0 = bf2f(uv & 0xffff), u1 = bf2f(uv >> 16);
        float du0 = d0 * u0, du1 = d1 * u1;
        float y0 = 0.f, y1 = 0.f;
#pragma unroll
        for (int n = 0; n < 8; ++n) {
            float bn = bc[l * 128 + 64 + n];
            float cn = bc[l * 128 + 72 + n];
            h[n]     = h[n]     * __expf(d0 * An[n])     + du0 * bn;
            h[8 + n] = h[8 + n] * __expf(d1 * An[8 + n]) + du1 * bn;
            y0 += h[n] * cn;
            y1 += h[8 + n] * cn;
        }
        y0 += u0 * Dp0; y1 += u1 * Dp1;
        unsigned zv = zrow[(long)l * 2048];
        float z0 = bf2f(zv & 0xffff), z1 = bf2f(zv >> 16);
        float g0 = z0 / (1.f + __expf(-z0));
        float g1 = z1 / (1.f + __expf(-z1));
        yrow[(long)l * 1024] = (unsigned)f2bf(y0 * g0) | ((unsigned)f2bf(y1 * g1) << 16);
    }
}

__global__ __launch_bounds__(256)
void rmsnorm_k(const unsigned short* __restrict__ in, const float* __restrict__ w,
               float* __restrict__ out)
{
    const int row = blockIdx.x;
    uint2 v2 = *(const uint2*)(in + (long)row * 1024 + threadIdx.x * 4);
    float x0 = bf2f(v2.x & 0xffff), x1 = bf2f(v2.x >> 16);
    float x2 = bf2f(v2.y & 0xffff), x3 = bf2f(v2.y >> 16);
    float ss = x0 * x0 + x1 * x1 + x2 * x2 + x3 * x3;
#pragma unroll
    for (int m = 32; m >= 1; m >>= 1) ss += __shfl_xor(ss, m, 64);
    __shared__ float wsum[4];
    const int wave = threadIdx.x >> 6;
    if ((threadIdx.x & 63) == 0) wsum[wave] = ss;
    __syncthreads();
    float tot = wsum[0] + wsum[1] + wsum[2] + wsum[3];
    float sc = rsqrtf(tot * (1.f / 1024.f) + 1e-5f);
    float4 wv = ((const float4*)w)[threadIdx.x];
    float4 o;
    o.x = x0 * sc * wv.x; o.y = x1 * sc * wv.y;
    o.z = x2 * sc * wv.z; o.w = x3 * sc * wv.w;
    ((float4*)(out + (long)row * 1024))[threadIdx.x] = o;
}

extern "C" void kernel_launch(void* const* d_in, const int* in_sizes, int n_in,
                              void* d_out, int out_size, void* d_ws, size_t ws_size,
                              hipStream_t stream)
{
    const float* inp   = (const float*)d_in[0];
    const float* w_in  = (const float*)d_in[1];
    const float* convw = (const float*)d_in[2];
    const float* convb = (const float*)d_in[3];
    const float* w_xp  = (const float*)d_in[4];
    const float* w_dt  = (const float*)d_in[5];
    const float* b_dt  = (const float*)d_in[6];
    const float* A_log = (const float*)d_in[7];
    const float* Dp    = (const float*)d_in[8];
    const float* w_out = (const float*)d_in[9];
    const float* rmsw  = (const float*)d_in[10];

    char* ws = (char*)d_ws;
    const size_t MB = 1024 * 1024;
    unsigned short* inp_bf   = (unsigned short*)(ws + 0);        // 16MB (dead after GEMM1)
    unsigned short* win_bf   = (unsigned short*)(ws + 16 * MB);  // 8MB  (dead after GEMM1)
    unsigned short* xz_bf    = (unsigned short*)(ws + 24 * MB);  // 64MB (live until scan_final)
    unsigned short* xconv_bf = (unsigned short*)(ws + 88 * MB);  // 32MB
    unsigned short* wxp_bf   = (unsigned short*)(ws + 120 * MB); // 0.5MB
    float*          dbc      = (float*)(ws + 121 * MB);          // 4MB
    unsigned short* dt_bf    = (unsigned short*)(ws + 125 * MB); // 1MB
    unsigned short* wdt_bf   = (unsigned short*)(ws + 126 * MB); // 0.25MB
    unsigned short* delta_bf = (unsigned short*)(ws + 127 * MB); // 32MB
    unsigned short* yg_bf    = (unsigned short*)(ws + 191 * MB); // 32MB
    unsigned short* wout_bf  = (unsigned short*)(ws + 223 * MB); // 4MB
    float*          dbc_part = (float*)(ws + 159 * MB);          // 16MB (xp partials; dead after reduce)
    float*          hend     = (float*)(ws + 159 * MB);          // 16MB (after reduce)
    float*          hin      = (float*)(ws + 175 * MB);          // 16MB
    float*          Ssum     = (float*)(ws + 0);                 // 2MB  (over dead inp_bf)
    unsigned short* out_pre  = (unsigned short*)(ws + 0);        // 16MB bf16 (after scans)

    hipFuncSetAttribute((const void*)gemm8p<1, 256>, hipFuncAttributeMaxDynamicSharedMemorySize, 131072);
    hipFuncSetAttribute((const void*)gemm8p<1, 128>, hipFuncAttributeMaxDynamicSharedMemorySize, 98304);

    cvt_all<<<2048, 256, 0, stream>>>(inp, w_in, w_xp, w_dt, w_out,
                                      inp_bf, win_bf, wxp_bf, wdt_bf, wout_bf);

    // xz = inp @ in_proj_w^T (8192 x 4096, K=1024) -> bf16
    gemm8p<1, 256><<<dim3(16, 32), 512, 131072, stream>>>(inp_bf, win_bf, xz_bf, 8192, 4096, 1024);
    // depthwise causal conv + silu
    conv_silu_k<<<dim3(64, 4, 4), 256, 0, stream>>>(xz_bf, convw, convb, xconv_bf);
    // dbc partials: xconv @ x_proj_w^T split-K (4 x 512) -- 256 blocks
    gemm_xp<<<dim3(64, 4), 256, 0, stream>>>(xconv_bf, wxp_bf, dbc_part);
    // reduce partials -> dbc f32 + dt bf16
    reduce_dbc<<<4096, 256, 0, stream>>>(dbc_part, dbc, dt_bf);
    // delta = softplus(dt @ dt_proj_w^T + b) -> bf16 (light 128^2 kernel, 1024 blocks)
    gemm_dt<<<dim3(16, 64), 256, 0, stream>>>(dt_bf, wdt_bf, b_dt, delta_bf);
    // chunked parallel SSM scan
    scan_local<<<dim3(4, NC, 4), 256, 0, stream>>>(delta_bf, xconv_bf, dbc, A_log, hend, Ssum);
    scan_combine<<<256, 256, 0, stream>>>(hend, Ssum, A_log, hin);
    scan_final<<<dim3(4, NC, 4), 256, 0, stream>>>(delta_bf, xconv_bf, dbc, xz_bf, A_log, Dp, hin, yg_bf);
    // out_pre = ygated @ out_proj_w^T (8192 x 1024, K=2048) -> bf16
    gemm8p<1, 128><<<dim3(8, 32), 512, 98304, stream>>>(yg_bf, wout_bf, out_pre, 8192, 1024, 2048);
    // RMSNorm (bf16 in, f32 out)
    rmsnorm_k<<<8192, 256, 0, stream>>>(out_pre, rmsw, (float*)d_out);
}

// Round 8
// 321.091 us; speedup vs baseline: 1.0558x; 1.0073x over previous
//
#include <hip/hip_runtime.h>

#define LL 2048
#define EE 2048
#define DD 1024
#define NC 64    // chunks along L
#define CH 32    // chunk length (NC*CH == LL)

typedef short bf16x8 __attribute__((ext_vector_type(8)));
typedef float f32x4 __attribute__((ext_vector_type(4)));

__device__ inline float bf2f(unsigned short u) {
    union { unsigned u; float f; } v; v.u = ((unsigned)u) << 16; return v.f;
}
__device__ inline unsigned short f2bf(float f) {
    union { float f; unsigned u; } v; v.f = f;
    unsigned r = v.u + 0x7fff + ((v.u >> 16) & 1);
    return (unsigned short)(r >> 16);
}

__device__ inline void gload_lds16(const void* g, void* lds) {
    __builtin_amdgcn_global_load_lds(
        (const __attribute__((address_space(1))) unsigned int*)g,
        (__attribute__((address_space(3))) unsigned int*)lds, 16, 0, 0);
}

// ================= 256xBN 8-phase counted-vmcnt GEMM =================
// XCD-strip mapping: hardware id lin -> XCD (lin%8); each XCD owns contiguous
// strips of STRIPE gy row-panels so A-panels stay L2-resident; B streams.
// MODE 0: f32 out. MODE 1: bf16 out.
template<int MODE, int BN, int STRIPE>
__global__ __launch_bounds__(512, 2)
void gemm8p(const unsigned short* __restrict__ A,
            const unsigned short* __restrict__ Bw,
            void* __restrict__ Cout,
            int M, int N, int K)
{
    constexpr int NREP = BN / 64;
    constexpr int RB   = BN / 128;
    constexpr int LH   = 2 + RB;
    constexpr int NSTRIP = BN / 4;

    extern __shared__ short lds[];
    short* Asm = lds;                    // [2buf][2kh][256][32]
    short* Bsm = lds + 2 * 2 * 256 * 32; // [2buf][2kh][BN][32]

    const int tid = threadIdx.x;
    const int w = tid >> 6, lane = tid & 63;
    const int wm = w >> 2, wn = w & 3;

    const int gx = N / BN;
    int lin = blockIdx.y * gx + blockIdx.x;
    // XCD-strip bijection (gy == M/256 must be divisible by STRIPE; chunks
    // round-robin over 8 XCDs). Correct for any lin->XCD reality (bijective).
    const int k = lin & 7, loc = lin >> 3;
    const int bpc = STRIPE * gx;          // blocks per chunk
    const int j = loc / bpc;              // chunk round on this XCD
    const int wi = loc % bpc;
    const int my = (k + 8 * j) * STRIPE + wi / gx;
    const int nx = wi % gx;
    const long m0 = (long)my * 256;
    const long n0 = (long)nx * BN;

    const int g = (tid & 3) ^ ((tid >> 3) & 3);
    const int arow = tid >> 2;
    const unsigned short* Ag = A + (m0 + arow) * (long)K + g * 8;
    const unsigned short* Bg = Bw + (n0 + arow) * (long)K + g * 8;
    const int ldsrow = w * 16;

    auto stageA = [&](int buf, int kh, int jj, int kt) {
        gload_lds16(Ag + (long)jj * 128 * K + kt * 64 + kh * 32,
                    Asm + ((buf * 2 + kh) * 256 + jj * 128 + ldsrow) * 32);
    };
    auto stageB = [&](int buf, int kh, int jj, int kt) {
        gload_lds16(Bg + (long)jj * 128 * K + kt * 64 + kh * 32,
                    Bsm + ((buf * 2 + kh) * BN + jj * 128 + ldsrow) * 32);
    };

    f32x4 acc[8][NREP] = {};

    stageA(0, 0, 0, 0); stageA(0, 0, 1, 0);
#pragma unroll
    for (int jj = 0; jj < RB; ++jj) stageB(0, 0, jj, 0);
    stageA(0, 1, 0, 0); stageA(0, 1, 1, 0);
#pragma unroll
    for (int jj = 0; jj < RB; ++jj) stageB(0, 1, jj, 0);

    const int NT = K / 64;
    const int rr = lane & 15;
    const int sl = ((lane >> 4) ^ ((rr >> 1) & 3)) * 8;

    for (int t = 0; t < NT; ++t) {
        const int cur = t & 1, nxt = cur ^ 1;
        const bool more = (t + 1 < NT);

        asm volatile("s_waitcnt vmcnt(%0)" :: "i"(LH) : "memory");
        __builtin_amdgcn_s_barrier();

        const short* Ac0 = Asm + (cur * 2 + 0) * 256 * 32;
        const short* Bc0 = Bsm + (cur * 2 + 0) * BN * 32;
        if (more) { stageA(nxt, 0, 0, t + 1); stageA(nxt, 0, 1, t + 1); }
        bf16x8 a[4], b[NREP];
#pragma unroll
        for (int m = 0; m < 4; ++m)
            a[m] = *(const bf16x8*)&Ac0[(wm * 128 + m * 16 + rr) * 32 + sl];
#pragma unroll
        for (int n = 0; n < NREP; ++n)
            b[n] = *(const bf16x8*)&Bc0[(wn * NSTRIP + n * 16 + rr) * 32 + sl];
        __builtin_amdgcn_s_setprio(1);
#pragma unroll
        for (int m = 0; m < 4; ++m)
#pragma unroll
            for (int n = 0; n < NREP; ++n)
                acc[m][n] = __builtin_amdgcn_mfma_f32_16x16x32_bf16(a[m], b[n], acc[m][n], 0, 0, 0);
        __builtin_amdgcn_s_setprio(0);
        if (more) {
#pragma unroll
            for (int jj = 0; jj < RB; ++jj) stageB(nxt, 0, jj, t + 1);
        }
#pragma unroll
        for (int m = 0; m < 4; ++m)
            a[m] = *(const bf16x8*)&Ac0[(wm * 128 + 64 + m * 16 + rr) * 32 + sl];
        __builtin_amdgcn_s_setprio(1);
#pragma unroll
        for (int m = 0; m < 4; ++m)
#pragma unroll
            for (int n = 0; n < NREP; ++n)
                acc[4 + m][n] = __builtin_amdgcn_mfma_f32_16x16x32_bf16(a[m], b[n], acc[4 + m][n], 0, 0, 0);
        __builtin_amdgcn_s_setprio(0);

        if (more) { asm volatile("s_waitcnt vmcnt(%0)" :: "i"(LH) : "memory"); }
        else      { asm volatile("s_waitcnt vmcnt(0)" ::: "memory"); }
        __builtin_amdgcn_s_barrier();

        const short* Ac1 = Asm + (cur * 2 + 1) * 256 * 32;
        const short* Bc1 = Bsm + (cur * 2 + 1) * BN * 32;
        if (more) { stageA(nxt, 1, 0, t + 1); stageA(nxt, 1, 1, t + 1); }
#pragma unroll
        for (int m = 0; m < 4; ++m)
            a[m] = *(const bf16x8*)&Ac1[(wm * 128 + m * 16 + rr) * 32 + sl];
#pragma unroll
        for (int n = 0; n < NREP; ++n)
            b[n] = *(const bf16x8*)&Bc1[(wn * NSTRIP + n * 16 + rr) * 32 + sl];
        __builtin_amdgcn_s_setprio(1);
#pragma unroll
        for (int m = 0; m < 4; ++m)
#pragma unroll
            for (int n = 0; n < NREP; ++n)
                acc[m][n] = __builtin_amdgcn_mfma_f32_16x16x32_bf16(a[m], b[n], acc[m][n], 0, 0, 0);
        __builtin_amdgcn_s_setprio(0);
        if (more) {
#pragma unroll
            for (int jj = 0; jj < RB; ++jj) stageB(nxt, 1, jj, t + 1);
        }
#pragma unroll
        for (int m = 0; m < 4; ++m)
            a[m] = *(const bf16x8*)&Ac1[(wm * 128 + 64 + m * 16 + rr) * 32 + sl];
        __builtin_amdgcn_s_setprio(1);
#pragma unroll
        for (int m = 0; m < 4; ++m)
#pragma unroll
            for (int n = 0; n < NREP; ++n)
                acc[4 + m][n] = __builtin_amdgcn_mfma_f32_16x16x32_bf16(a[m], b[n], acc[4 + m][n], 0, 0, 0);
        __builtin_amdgcn_s_setprio(0);
    }

#pragma unroll
    for (int m = 0; m < 8; ++m) {
#pragma unroll
        for (int n = 0; n < NREP; ++n) {
#pragma unroll
            for (int r = 0; r < 4; ++r) {
                long row = m0 + wm * 128 + m * 16 + (lane >> 4) * 4 + r;
                long col = n0 + wn * NSTRIP + n * 16 + (lane & 15);
                float v = acc[m][n][r];
                if (MODE == 0) ((float*)Cout)[row * N + col] = v;
                else           ((unsigned short*)Cout)[row * N + col] = f2bf(v);
            }
        }
    }
}

// ============ x_proj split-K GEMM: 128x128 tile, K-slice 512, kz 0..3 ============
__global__ __launch_bounds__(256)
void gemm_xp(const unsigned short* __restrict__ A,
             const unsigned short* __restrict__ Bw,
             float* __restrict__ Cout)
{
    __shared__ short As[128 * 32];
    __shared__ short Bs[128 * 32];
    const int tid = threadIdx.x;
    const int wave = tid >> 6, lane = tid & 63;
    const int wm = wave >> 1, wn = wave & 1;
    const long m0 = (long)blockIdx.x * 128;
    const int kz = blockIdx.y;
    float* out = Cout + (long)kz * 8192 * 128;

    f32x4 acc[4][4] = {};

    const int srow = lane >> 2;
    const int g = (lane & 3) ^ ((srow >> 1) & 3);
    const int c0 = wave, c1 = wave + 4;

    for (int k0 = kz * 512; k0 < kz * 512 + 512; k0 += 32) {
        gload_lds16(A + (m0 + c0 * 16 + srow) * 2048L + k0 + g * 8, &As[c0 * 16 * 32]);
        gload_lds16(A + (m0 + c1 * 16 + srow) * 2048L + k0 + g * 8, &As[c1 * 16 * 32]);
        gload_lds16(Bw + (c0 * 16 + srow) * 2048L + k0 + g * 8, &Bs[c0 * 16 * 32]);
        gload_lds16(Bw + (c1 * 16 + srow) * 2048L + k0 + g * 8, &Bs[c1 * 16 * 32]);
        __syncthreads();

        const int rr = lane & 15;
        const int sl = ((lane >> 4) ^ ((rr >> 1) & 3)) * 8;
        bf16x8 af[4], bfr[4];
#pragma unroll
        for (int m = 0; m < 4; ++m)
            af[m] = *(const bf16x8*)&As[(wm * 64 + m * 16 + rr) * 32 + sl];
#pragma unroll
        for (int n = 0; n < 4; ++n)
            bfr[n] = *(const bf16x8*)&Bs[(wn * 64 + n * 16 + rr) * 32 + sl];
#pragma unroll
        for (int m = 0; m < 4; ++m)
#pragma unroll
            for (int n = 0; n < 4; ++n)
                acc[m][n] = __builtin_amdgcn_mfma_f32_16x16x32_bf16(af[m], bfr[n], acc[m][n], 0, 0, 0);
        __syncthreads();
    }

#pragma unroll
    for (int m = 0; m < 4; ++m)
#pragma unroll
        for (int n = 0; n < 4; ++n)
#pragma unroll
            for (int r = 0; r < 4; ++r) {
                long row = m0 + wm * 64 + m * 16 + (lane >> 4) * 4 + r;
                long col = wn * 64 + n * 16 + (lane & 15);
                out[row * 128 + col] = acc[m][n][r];
            }
}

// sum 4 K-partials -> dbc f32; cols < 64 also -> dt bf16
__global__ void reduce_dbc(const float* __restrict__ part,
                           float* __restrict__ dbc,
                           unsigned short* __restrict__ dt)
{
    const long i = (long)blockIdx.x * 256 + threadIdx.x;
    float s = part[i] + part[i + 1048576] + part[i + 2 * 1048576] + part[i + 3 * 1048576];
    dbc[i] = s;
    const int c = (int)(i & 127);
    if (c < 64) dt[(i >> 7) * 64 + c] = f2bf(s);
}

// ===== dt_proj: light 128x128 2-phase GEMM, K=64 (16KB LDS -> multi-block/CU) =====
__global__ __launch_bounds__(256)
void gemm_dt(const unsigned short* __restrict__ A,
             const unsigned short* __restrict__ Bw,
             const float* __restrict__ bias,
             unsigned short* __restrict__ Cout)
{
    __shared__ short As[128 * 32];
    __shared__ short Bs[128 * 32];
    const int tid = threadIdx.x;
    const int wave = tid >> 6, lane = tid & 63;
    const int wm = wave >> 1, wn = wave & 1;
    const long m0 = (long)blockIdx.y * 128;
    const long n0 = (long)blockIdx.x * 128;

    f32x4 acc[4][4] = {};

    const int srow = lane >> 2;
    const int g = (lane & 3) ^ ((srow >> 1) & 3);
    const int c0 = wave, c1 = wave + 4;

    for (int k0 = 0; k0 < 64; k0 += 32) {
        gload_lds16(A + (m0 + c0 * 16 + srow) * 64L + k0 + g * 8, &As[c0 * 16 * 32]);
        gload_lds16(A + (m0 + c1 * 16 + srow) * 64L + k0 + g * 8, &As[c1 * 16 * 32]);
        gload_lds16(Bw + (n0 + c0 * 16 + srow) * 64L + k0 + g * 8, &Bs[c0 * 16 * 32]);
        gload_lds16(Bw + (n0 + c1 * 16 + srow) * 64L + k0 + g * 8, &Bs[c1 * 16 * 32]);
        __syncthreads();

        const int rr = lane & 15;
        const int sl = ((lane >> 4) ^ ((rr >> 1) & 3)) * 8;
        bf16x8 af[4], bfr[4];
#pragma unroll
        for (int m = 0; m < 4; ++m)
            af[m] = *(const bf16x8*)&As[(wm * 64 + m * 16 + rr) * 32 + sl];
#pragma unroll
        for (int n = 0; n < 4; ++n)
            bfr[n] = *(const bf16x8*)&Bs[(wn * 64 + n * 16 + rr) * 32 + sl];
#pragma unroll
        for (int m = 0; m < 4; ++m)
#pragma unroll
            for (int n = 0; n < 4; ++n)
                acc[m][n] = __builtin_amdgcn_mfma_f32_16x16x32_bf16(af[m], bfr[n], acc[m][n], 0, 0, 0);
        __syncthreads();
    }

#pragma unroll
    for (int m = 0; m < 4; ++m)
#pragma unroll
        for (int n = 0; n < 4; ++n)
#pragma unroll
            for (int r = 0; r < 4; ++r) {
                long row = m0 + wm * 64 + m * 16 + (lane >> 4) * 4 + r;
                long col = n0 + wn * 64 + n * 16 + (lane & 15);
                float v = acc[m][n][r] + bias[col];
                float sp = (v > 20.f) ? v : log1pf(__expf(v));
                Cout[row * 2048 + col] = f2bf(sp);
            }
}

// ---- all f32->bf16 operand conversions in ONE launch ----
__device__ inline void cvt4(const float* __restrict__ in, unsigned short* __restrict__ out, long i) {
    float4 v = ((const float4*)in)[i];
    unsigned lo = (unsigned)f2bf(v.x) | ((unsigned)f2bf(v.y) << 16);
    unsigned hi = (unsigned)f2bf(v.z) | ((unsigned)f2bf(v.w) << 16);
    ((uint2*)out)[i] = make_uint2(lo, hi);
}

__global__ void cvt_all(const float* __restrict__ inp, const float* __restrict__ w_in,
                        const float* __restrict__ w_xp, const float* __restrict__ w_dt,
                        const float* __restrict__ w_out,
                        unsigned short* __restrict__ o_inp, unsigned short* __restrict__ o_win,
                        unsigned short* __restrict__ o_wxp, unsigned short* __restrict__ o_wdt,
                        unsigned short* __restrict__ o_wout)
{
    const long t = (long)blockIdx.x * 256 + threadIdx.x;
    const long gs = (long)gridDim.x * 256;
    for (long i = t; i < 8388608 / 4; i += gs) cvt4(inp, o_inp, i);
    for (long i = t; i < 4194304 / 4; i += gs) cvt4(w_in, o_win, i);
    for (long i = t; i < 2097152 / 4; i += gs) cvt4(w_out, o_wout, i);
    for (long i = t; i < 131072 / 4; i += gs) cvt4(w_dt, o_wdt, i);
    for (long i = t; i < 262144 / 4; i += gs) {
        const int r = (int)(i >> 9);
        if (r < 80) cvt4(w_xp, o_wxp, i);
        else ((uint2*)o_wxp)[i] = make_uint2(0u, 0u);
    }
}

// depthwise causal conv (K=4) + bias + silu; 2 channels per thread (u32 I/O).
__global__ void conv_silu_k(const unsigned short* __restrict__ xz,
                            const float* __restrict__ cw,
                            const float* __restrict__ cb,
                            unsigned short* __restrict__ xc)
{
    const int ep = blockIdx.y * 256 + threadIdx.x;
    const int e0 = ep * 2, e1 = e0 + 1;
    const int b = blockIdx.z;
    const int l0 = blockIdx.x * 32;
    const float wa0 = cw[e0 * 4], wa1 = cw[e0 * 4 + 1], wa2 = cw[e0 * 4 + 2], wa3 = cw[e0 * 4 + 3];
    const float wb0 = cw[e1 * 4], wb1 = cw[e1 * 4 + 1], wb2 = cw[e1 * 4 + 2], wb3 = cw[e1 * 4 + 3];
    const float ba = cb[e0], bb = cb[e1];
    const unsigned* xrow = (const unsigned*)(xz + (long)b * LL * 4096) + ep;
    unsigned* orow = (unsigned*)(xc + (long)b * LL * 2048) + ep;

    float a3 = 0.f, a2 = 0.f, a1 = 0.f, b3 = 0.f, b2 = 0.f, b1 = 0.f;
    if (l0 >= 3) { unsigned u = xrow[(long)(l0 - 3) * 2048]; a3 = bf2f(u & 0xffff); b3 = bf2f(u >> 16); }
    if (l0 >= 2) { unsigned u = xrow[(long)(l0 - 2) * 2048]; a2 = bf2f(u & 0xffff); b2 = bf2f(u >> 16); }
    if (l0 >= 1) { unsigned u = xrow[(long)(l0 - 1) * 2048]; a1 = bf2f(u & 0xffff); b1 = bf2f(u >> 16); }
    for (int l = l0; l < l0 + 32; ++l) {
        unsigned u = xrow[(long)l * 2048];
        float xa = bf2f(u & 0xffff), xb = bf2f(u >> 16);
        float va = ba + wa0 * a3 + wa1 * a2 + wa2 * a1 + wa3 * xa;
        float vb = bb + wb0 * b3 + wb1 * b2 + wb2 * b1 + wb3 * xb;
        float sa = va / (1.f + __expf(-va));
        float sb = vb / (1.f + __expf(-vb));
        orow[(long)l * 1024] = (unsigned)f2bf(sa) | ((unsigned)f2bf(sb) << 16);
        a3 = a2; a2 = a1; a1 = xa;
        b3 = b2; b2 = b1; b1 = xb;
    }
}

// ------- chunked parallel SSM scan, 2 channels/thread (NC=64, CH=32) -------
__global__ __launch_bounds__(256)
void scan_local(const unsigned short* __restrict__ delta,
                const unsigned short* __restrict__ xconv,
                const float* __restrict__ dbc,
                const float* __restrict__ A_log,
                float* __restrict__ hend, float* __restrict__ Ssum)
{
    const int ep = blockIdx.x * 256 + threadIdx.x;
    const int e0 = ep * 2;
    const int c = blockIdx.y, b = blockIdx.z;
    const int l0 = c * CH;
    float An[16];
#pragma unroll
    for (int n = 0; n < 16; ++n) An[n] = -__expf(A_log[e0 * 8 + n]);
    float h[16] = {};
    float S0 = 0.f, S1 = 0.f;
    const unsigned* drow = (const unsigned*)(delta + ((long)b * LL + l0) * EE) + ep;
    const unsigned* urow = (const unsigned*)(xconv + ((long)b * LL + l0) * EE) + ep;
    const float* bc = dbc + ((long)b * LL + l0) * 128;
    for (int l = 0; l < CH; ++l) {
        unsigned dv = drow[(long)l * 1024];
        unsigned uv = urow[(long)l * 1024];
        float d0 = bf2f(dv & 0xffff), d1 = bf2f(dv >> 16);
        float u0 = bf2f(uv & 0xffff), u1 = bf2f(uv >> 16);
        float du0 = d0 * u0, du1 = d1 * u1;
        S0 += d0; S1 += d1;
#pragma unroll
        for (int n = 0; n < 8; ++n) {
            float bn = bc[l * 128 + 64 + n];
            h[n]     = h[n]     * __expf(d0 * An[n])     + du0 * bn;
            h[8 + n] = h[8 + n] * __expf(d1 * An[8 + n]) + du1 * bn;
        }
    }
    const long o = ((long)b * NC + c) * EE + e0;
#pragma unroll
    for (int n = 0; n < 8; ++n) { hend[o * 8 + n] = h[n]; hend[(o + 1) * 8 + n] = h[8 + n]; }
    Ssum[o] = S0; Ssum[o + 1] = S1;
}

// combine parallelized over (b,e,n): 65536 threads = 256 blocks.
__global__ __launch_bounds__(256)
void scan_combine(const float* __restrict__ hend, const float* __restrict__ Ssum,
                  const float* __restrict__ A_log, float* __restrict__ hin)
{
    const int t = blockIdx.x * 256 + threadIdx.x;
    const int n = t & 7;
    const int be = t >> 3;
    const int b = be >> 11, e = be & 2047;
    const float An = -__expf(A_log[e * 8 + n]);
    float h = 0.f;
    for (int c = 0; c < NC; ++c) {
        const long o = ((long)b * NC + c) * EE + e;
        hin[o * 8 + n] = h;
        h = h * __expf(An * Ssum[o]) + hend[o * 8 + n];
    }
}

__global__ __launch_bounds__(256)
void scan_final(const unsigned short* __restrict__ delta,
                const unsigned short* __restrict__ xconv,
                const float* __restrict__ dbc,
                const unsigned short* __restrict__ xz,
                const float* __restrict__ A_log,
                const float* __restrict__ Dparam,
                const float* __restrict__ hin,
                unsigned short* __restrict__ yg)
{
    const int ep = blockIdx.x * 256 + threadIdx.x;
    const int e0 = ep * 2;
    const int c = blockIdx.y, b = blockIdx.z;
    const int l0 = c * CH;
    float An[16];
#pragma unroll
    for (int n = 0; n < 16; ++n) An[n] = -__expf(A_log[e0 * 8 + n]);
    const float Dp0 = Dparam[e0], Dp1 = Dparam[e0 + 1];
    float h[16];
    const long o = ((long)b * NC + c) * EE + e0;
#pragma unroll
    for (int n = 0; n < 8; ++n) { h[n] = hin[o * 8 + n]; h[8 + n] = hin[(o + 1) * 8 + n]; }
    const unsigned* drow = (const unsigned*)(delta + ((long)b * LL + l0) * EE) + ep;
    const unsigned* urow = (const unsigned*)(xconv + ((long)b * LL + l0) * EE) + ep;
    const unsigned* zrow = (const unsigned*)(xz + ((long)b * LL + l0) * 4096 + 2048) + ep;
    const float* bc = dbc + ((long)b * LL + l0) * 128;
    unsigned* yrow = (unsigned*)(yg + ((long)b * LL + l0) * EE) + ep;
    for (int l = 0; l < CH; ++l) {
        unsigned dv = drow[(long)l * 1024];
        unsigned uv = urow[(long)l * 1024];
        float d0 = bf2f(dv & 0xffff), d1 = bf2f(dv >> 16);
        float u0 = bf2f(uv & 0xffff), u1 = bf2f(uv >> 16);
        float du0 = d0 * u0, du1 = d1 * u1;
        float y0 = 0.f, y1 = 0.f;
#pragma unroll
        for (int n = 0; n < 8; ++n) {
            float bn = bc[l * 128 + 64 + n];
            float cn = bc[l * 128 + 72 + n];
            h[n]     = h[n]     * __expf(d0 * An[n])     + du0 * bn;
            h[8 + n] = h[8 + n] * __expf(d1 * An[8 + n]) + du1 * bn;
            y0 += h[n] * cn;
            y1 += h[8 + n] * cn;
        }
        y0 += u0 * Dp0; y1 += u1 * Dp1;
        unsigned zv = zrow[(long)l * 2048];
        float z0 = bf2f(zv & 0xffff), z1 = bf2f(zv >> 16);
        float g0 = z0 / (1.f + __expf(-z0));
        float g1 = z1 / (1.f + __expf(-z1));
        yrow[(long)l * 1024] = (unsigned)f2bf(y0 * g0) | ((unsigned)f2bf(y1 * g1) << 16);
    }
}

__global__ __launch_bounds__(256)
void rmsnorm_k(const unsigned short* __restrict__ in, const float* __restrict__ w,
               float* __restrict__ out)
{
    const int row = blockIdx.x;
    uint2 v2 = *(const uint2*)(in + (long)row * 1024 + threadIdx.x * 4);
    float x0 = bf2f(v2.x & 0xffff), x1 = bf2f(v2.x >> 16);
    float x2 = bf2f(v2.y & 0xffff), x3 = bf2f(v2.y >> 16);
    float ss = x0 * x0 + x1 * x1 + x2 * x2 + x3 * x3;
#pragma unroll
    for (int m = 32; m >= 1; m >>= 1) ss += __shfl_xor(ss, m, 64);
    __shared__ float wsum[4];
    const int wave = threadIdx.x >> 6;
    if ((threadIdx.x & 63) == 0) wsum[wave] = ss;
    __syncthreads();
    float tot = wsum[0] + wsum[1] + wsum[2] + wsum[3];
    float sc = rsqrtf(tot * (1.f / 1024.f) + 1e-5f);
    float4 wv = ((const float4*)w)[threadIdx.x];
    float4 o;
    o.x = x0 * sc * wv.x; o.y = x1 * sc * wv.y;
    o.z = x2 * sc * wv.z; o.w = x3 * sc * wv.w;
    ((float4*)(out + (long)row * 1024))[threadIdx.x] = o;
}

extern "C" void kernel_launch(void* const* d_in, const int* in_sizes, int n_in,
                              void* d_out, int out_size, void* d_ws, size_t ws_size,
                              hipStream_t stream)
{
    const float* inp   = (const float*)d_in[0];
    const float* w_in  = (const float*)d_in[1];
    const float* convw = (const float*)d_in[2];
    const float* convb = (const float*)d_in[3];
    const float* w_xp  = (const float*)d_in[4];
    const float* w_dt  = (const float*)d_in[5];
    const float* b_dt  = (const float*)d_in[6];
    const float* A_log = (const float*)d_in[7];
    const float* Dp    = (const float*)d_in[8];
    const float* w_out = (const float*)d_in[9];
    const float* rmsw  = (const float*)d_in[10];

    char* ws = (char*)d_ws;
    const size_t MB = 1024 * 1024;
    unsigned short* inp_bf   = (unsigned short*)(ws + 0);        // 16MB (dead after GEMM1)
    unsigned short* win_bf   = (unsigned short*)(ws + 16 * MB);  // 8MB  (dead after GEMM1)
    unsigned short* xz_bf    = (unsigned short*)(ws + 24 * MB);  // 64MB (live until scan_final)
    unsigned short* xconv_bf = (unsigned short*)(ws + 88 * MB);  // 32MB
    unsigned short* wxp_bf   = (unsigned short*)(ws + 120 * MB); // 0.5MB
    float*          dbc      = (float*)(ws + 121 * MB);          // 4MB
    unsigned short* dt_bf    = (unsigned short*)(ws + 125 * MB); // 1MB
    unsigned short* wdt_bf   = (unsigned short*)(ws + 126 * MB); // 0.25MB
    unsigned short* delta_bf = (unsigned short*)(ws + 127 * MB); // 32MB
    unsigned short* yg_bf    = (unsigned short*)(ws + 191 * MB); // 32MB
    unsigned short* wout_bf  = (unsigned short*)(ws + 223 * MB); // 4MB
    float*          dbc_part = (float*)(ws + 159 * MB);          // 16MB (xp partials)
    float*          hend     = (float*)(ws + 159 * MB);          // 16MB (after reduce)
    float*          hin      = (float*)(ws + 175 * MB);          // 16MB
    float*          Ssum     = (float*)(ws + 0);                 // 2MB  (over dead inp_bf)
    unsigned short* out_pre  = (unsigned short*)(ws + 0);        // 16MB bf16 (after scans)

    hipFuncSetAttribute((const void*)gemm8p<1, 256, 4>, hipFuncAttributeMaxDynamicSharedMemorySize, 131072);
    hipFuncSetAttribute((const void*)gemm8p<1, 128, 2>, hipFuncAttributeMaxDynamicSharedMemorySize, 98304);

    cvt_all<<<2048, 256, 0, stream>>>(inp, w_in, w_xp, w_dt, w_out,
                                      inp_bf, win_bf, wxp_bf, wdt_bf, wout_bf);

    // xz = inp @ in_proj_w^T (8192 x 4096, K=1024) -> bf16; XCD strips of 4 gy
    gemm8p<1, 256, 4><<<dim3(16, 32), 512, 131072, stream>>>(inp_bf, win_bf, xz_bf, 8192, 4096, 1024);
    // depthwise causal conv + silu
    conv_silu_k<<<dim3(64, 4, 4), 256, 0, stream>>>(xz_bf, convw, convb, xconv_bf);
    // dbc partials: xconv @ x_proj_w^T split-K (4 x 512)
    gemm_xp<<<dim3(64, 4), 256, 0, stream>>>(xconv_bf, wxp_bf, dbc_part);
    // reduce partials -> dbc f32 + dt bf16
    reduce_dbc<<<4096, 256, 0, stream>>>(dbc_part, dbc, dt_bf);
    // delta = softplus(dt @ dt_proj_w^T + b) -> bf16
    gemm_dt<<<dim3(16, 64), 256, 0, stream>>>(dt_bf, wdt_bf, b_dt, delta_bf);
    // chunked parallel SSM scan
    scan_local<<<dim3(4, NC, 4), 256, 0, stream>>>(delta_bf, xconv_bf, dbc, A_log, hend, Ssum);
    scan_combine<<<256, 256, 0, stream>>>(hend, Ssum, A_log, hin);
    scan_final<<<dim3(4, NC, 4), 256, 0, stream>>>(delta_bf, xconv_bf, dbc, xz_bf, A_log, Dp, hin, yg_bf);
    // out_pre = ygated @ out_proj_w^T (8192 x 1024, K=2048) -> bf16; XCD strips of 2 gy
    gemm8p<1, 128, 2><<<dim3(8, 32), 512, 98304, stream>>>(yg_bf, wout_bf, out_pre, 8192, 1024, 2048);
    // RMSNorm (bf16 in, f32 out)
    rmsnorm_k<<<8192, 256, 0, stream>>>(out_pre, rmsw, (float*)d_out);
}